// Round 5
// baseline (273.386 us; speedup 1.0000x reference)
//
#include <hip/hip_runtime.h>
#include <hip/hip_bf16.h>
#include <stdint.h>

#define BLOCK 256
#define MAXO 64
#define TK_THREADS 1024
#define CK_MAX 4096

typedef float f32x4 __attribute__((ext_vector_type(4)));

// forced burst load: compiler cannot split/serialize; output regs pinned live
#define GLD(dst, base, off) \
    asm volatile("global_load_dwordx4 %0, %1, off offset:" #off \
                 : "=v"(dst) : "v"(base))

// ---------------- K1: per-object argmax over P (block per (n,o)) + init ----------------
__global__ void match_object_kernel(const float* __restrict__ boxes,
                                    const float* __restrict__ priors,
                                    int* __restrict__ pfop,
                                    float* __restrict__ acc, int* __restrict__ n_pos,
                                    unsigned* __restrict__ done, int N, int P, int O) {
    __shared__ unsigned long long swm[4];
    int idx = blockIdx.x, tid = threadIdx.x;
    if (idx == 0) {                       // init for later dispatches (stream-ordered)
        for (int j = tid; j < N; j += BLOCK) n_pos[j] = 0;
        if (tid >= 64 && tid < 67) acc[tid - 64] = 0.f;
        if (tid == 96) *done = 0u;
    }
    const float* b = boxes + (size_t)idx * 4;
    float bx0 = b[0], by0 = b[1], bx1 = b[2], by1 = b[3];
    float areaa = (bx1 - bx0) * (by1 - by0);

    unsigned long long best = 0ULL;
    for (int p = tid; p < P; p += BLOCK) {
        float4 pr = ((const float4*)priors)[p];
        float px0 = pr.x - pr.z * 0.5f, py0 = pr.y - pr.w * 0.5f;
        float px1 = pr.x + pr.z * 0.5f, py1 = pr.y + pr.w * 0.5f;
        float areab = (px1 - px0) * (py1 - py0);
        float ltx = fmaxf(bx0, px0), lty = fmaxf(by0, py0);
        float rbx = fminf(bx1, px1), rby = fminf(by1, py1);
        float wx = fmaxf(rbx - ltx, 0.f), wy = fmaxf(rby - lty, 0.f);
        float inter = wx * wy;
        float iou = inter / (areaa + areab - inter);
        unsigned long long cand = (((unsigned long long)__float_as_uint(iou)) << 32) |
                                  (unsigned long long)(0xFFFFFFFFu - (unsigned)p);
        if (cand > best) best = cand;     // larger iou; tie -> smaller p (numpy first)
    }
    #pragma unroll
    for (int off = 32; off >= 1; off >>= 1) {
        unsigned long long other = __shfl_down(best, off);
        if (other > best) best = other;
    }
    if ((tid & 63) == 0) swm[tid >> 6] = best;
    __syncthreads();
    if (tid == 0) {
        unsigned long long r = swm[0];
        for (int w = 1; w < BLOCK / 64; ++w) if (swm[w] > r) r = swm[w];
        pfop[idx] = (int)(0xFFFFFFFFu - (unsigned)(r & 0xFFFFFFFFull));
    }
}

// ---------------- K2+K3 fused v5: asm-burst register loads, C=81 ----------------
// Round-2 finding: compiler batches the 21 row loads in ~4-vector dribbles with a
// waitcnt each -> ~2.6KB/CU outstanding, latency-bound at 1.7TB/s. Rounds 3/4: the
// monolithic DMA-drain alternative is worse (2 blocks/CU convoy). v5: force the full
// 21x16B burst per lane via inline asm (outputs pinned in 84 VGPRs), run the match
// phase (LDS-broadcast + VALU only, no VMEM) under the flight, then one manual
// s_waitcnt vmcnt(0) + sched_barrier(0) (rule-18 fence) before the exp-sum consume.
// All compiler loads (meta/priors/locs) drain at the staging __syncthreads, so no
// compiler vmcnt wait lands inside the burst window. 21KB in flight per wave.
__global__ void __launch_bounds__(BLOCK, 4)
fused_match_ce_kernel(const float* __restrict__ boxes,
                      const float* __restrict__ priors,
                      const float* __restrict__ locs,
                      const int* __restrict__ labels,
                      const int* __restrict__ pfop,
                      const float* __restrict__ scores,
                      float* __restrict__ ce_neg,
                      float* __restrict__ acc, int* __restrict__ n_pos,
                      int N, int P, int O) {
    __shared__ float sbx[MAXO * 4];
    __shared__ int   spf[MAXO];
    __shared__ int   slab[MAXO];
    int n = blockIdx.y, tid = threadIdx.x;
    int p = blockIdx.x * BLOCK + tid;
    bool valid = p < P;                 // P%4==0 -> whole quads valid or invalid
    int lane = tid & 63;
    int s = tid & 3;

    // ---- compiler loads: metadata -> LDS, prior/loc -> regs (drained at barrier) ----
    if (tid < O * 4) sbx[tid] = boxes[(size_t)n * O * 4 + tid];
    if (tid >= 128 && tid < 128 + O) spf[tid - 128]  = pfop[n * O + (tid - 128)];
    if (tid >= 192 && tid < 192 + O) slab[tid - 192] = labels[n * O + (tid - 192)];
    float4 pr = make_float4(0.f, 0.f, 1.f, 1.f);
    float4 pl = make_float4(0.f, 0.f, 0.f, 0.f);
    size_t t = (size_t)n * P + p;
    if (valid) {
        pr = ((const float4*)priors)[p];
        pl = ((const float4*)locs)[t];
    }
    __syncthreads();   // vmcnt(0)+lgkmcnt(0) drain: compiler has nothing pending after

    // ---- forced burst: 21 x global_load_dwordx4 per lane (quad super-row) ----
    size_t NPt = (size_t)N * P;
    size_t tcl = (t < NPt) ? t : (NPt - 4);       // clamp keeps invalid quads in-bounds
    const f32x4* q  = (const f32x4*)scores + (tcl >> 2) * 81;
    const f32x4* qa = q + ((s == 0) ? 0 : (20 * s + 1));
    const f32x4* vbp = q + 20 * (s + 1);

    f32x4 v[19]; f32x4 v19, vb;
    GLD(v[0],  qa, 0);   GLD(v[1],  qa, 16);  GLD(v[2],  qa, 32);
    GLD(v[3],  qa, 48);  GLD(v[4],  qa, 64);  GLD(v[5],  qa, 80);
    GLD(v[6],  qa, 96);  GLD(v[7],  qa, 112); GLD(v[8],  qa, 128);
    GLD(v[9],  qa, 144); GLD(v[10], qa, 160); GLD(v[11], qa, 176);
    GLD(v[12], qa, 192); GLD(v[13], qa, 208); GLD(v[14], qa, 224);
    GLD(v[15], qa, 240); GLD(v[16], qa, 256); GLD(v[17], qa, 272);
    GLD(v[18], qa, 288);
    GLD(v19, q, 304);                     // element 19 of the quad base
    GLD(vb,  vbp, 0);                     // boundary vector (runtime offset)

    // ---- match phase under the burst flight: LDS broadcast + VALU, no VMEM ----
    float my_loc = 0.f, my_pce = 0.f; int my_pos = 0; int tc = 0;
    if (valid) {
        float px0 = pr.x - pr.z * 0.5f, py0 = pr.y - pr.w * 0.5f;
        float px1 = pr.x + pr.z * 0.5f, py1 = pr.y + pr.w * 0.5f;
        float areab = (px1 - px0) * (py1 - py0);

        float best = -1.f; int bo = 0;
        for (int o = 0; o < O; ++o) {             // sbx reads wave-broadcast
            float x0 = sbx[o*4+0], y0 = sbx[o*4+1], x1 = sbx[o*4+2], y1 = sbx[o*4+3];
            float ltx = fmaxf(x0, px0), lty = fmaxf(y0, py0);
            float rbx = fminf(x1, px1), rby = fminf(y1, py1);
            float wx = fmaxf(rbx - ltx, 0.f), wy = fmaxf(rby - lty, 0.f);
            float inter = wx * wy;
            float areao = (x1 - x0) * (y1 - y0);
            float iou = inter / (areao + areab - inter);
            if (iou > best) { best = iou; bo = o; }   // strict > = numpy first-index
        }
        int fo = -1;
        for (int o = 0; o < O; ++o) if (spf[o] == p) fo = o;   // last-wins scatter
        int obj; float ov;
        if (fo >= 0) { obj = fo; ov = 1.0f; }
        else         { obj = bo; ov = best; }
        tc = (ov < 0.5f) ? 0 : slab[obj];
        if (tc != 0) {
            my_pos = 1;
            float x0 = sbx[obj*4+0], y0 = sbx[obj*4+1], x1 = sbx[obj*4+2], y1 = sbx[obj*4+3];
            float cx = (x0 + x1) * 0.5f, cy = (y0 + y1) * 0.5f;
            float w = x1 - x0, h = y1 - y0;
            float g0 = (cx - pr.x) / (pr.z / 10.0f);
            float g1 = (cy - pr.y) / (pr.w / 10.0f);
            float g2 = logf(w / pr.z) * 5.0f;
            float g3 = logf(h / pr.w) * 5.0f;
            my_loc = fabsf(pl.x-g0) + fabsf(pl.y-g1) + fabsf(pl.z-g2) + fabsf(pl.w-g3);
        }
    }

    asm volatile("s_waitcnt vmcnt(0)" ::: "memory");  // burst drained exactly here
    __builtin_amdgcn_sched_barrier(0);                // rule-18: no consume hoisted above

    // ---- CE consume: quad of lanes owns 4 rows (324 floats = 81 float4) ----
    if (valid) {
        float a0 = 0.f, a1 = 0.f, a2 = 0.f, a3 = 0.f;
        #pragma unroll
        for (int j = 0; j < 19; ++j) {
            a0 += __expf(v[j][0]); a1 += __expf(v[j][1]);
            a2 += __expf(v[j][2]); a3 += __expf(v[j][3]);
        }
        float A = (a0 + a1) + (a2 + a3);
        if (s == 0) A += __expf(v19[0]) + __expf(v19[1]) + __expf(v19[2]) + __expf(v19[3]);
        float B = 0.f;
        {   // boundary: first s+1 components -> my row, rest spill to next row
            float ex = __expf(vb[0]), ey = __expf(vb[1]), ez = __expf(vb[2]), ew = __expf(vb[3]);
            A += ex;
            A += (s >= 1) ? ey : 0.f;   B += (s >= 1) ? 0.f : ey;
            A += (s >= 2) ? ez : 0.f;   B += (s >= 2) ? 0.f : ez;
            A += (s == 3) ? ew : 0.f;   B += (s == 3) ? 0.f : ew;
        }
        int src = (lane & ~3) | ((s + 3) & 3);
        float l = A + __shfl(B, src);                    // lane3's B==0 closes rotation

        float stc = scores[t * 81 + tc];                 // L1-hot (just streamed)
        float ce = logf(l) - stc;
        ce_neg[t] = (tc != 0) ? 0.f : ce;
        if (tc != 0) my_pce = ce;
    }

    #pragma unroll
    for (int off = 32; off >= 1; off >>= 1) {
        my_loc += __shfl_down(my_loc, off);
        my_pce += __shfl_down(my_pce, off);
        my_pos += __shfl_down(my_pos, off);
    }
    if ((tid & 63) == 0) {
        if (my_pos) {
            atomicAdd(&acc[0], my_loc);
            atomicAdd(&n_pos[n], my_pos);
        }
        if (my_pce != 0.f) atomicAdd(&acc[1], my_pce);
    }
}

// ---------------- fallback K2: per-prior match -> tcarr (any C path) ----------------
__global__ void match_prior_kernel(const float* __restrict__ boxes,
                                   const float* __restrict__ priors,
                                   const float* __restrict__ locs,
                                   const int* __restrict__ labels,
                                   const int* __restrict__ pfop,
                                   int* __restrict__ tcarr,
                                   float* __restrict__ acc, int* __restrict__ n_pos,
                                   int N, int P, int O) {
    __shared__ float sbx[MAXO * 4];
    __shared__ float sarea[MAXO];
    __shared__ int   spf[MAXO];
    __shared__ int   slab[MAXO];
    int n = blockIdx.y, tid = threadIdx.x;
    if (tid < O * 4) sbx[tid] = boxes[(size_t)n * O * 4 + tid];
    if (tid >= 128 && tid < 128 + O) spf[tid - 128]  = pfop[n * O + (tid - 128)];
    if (tid >= 192 && tid < 192 + O) slab[tid - 192] = labels[n * O + (tid - 192)];
    __syncthreads();
    if (tid < O)
        sarea[tid] = (sbx[tid*4+2] - sbx[tid*4+0]) * (sbx[tid*4+3] - sbx[tid*4+1]);
    __syncthreads();

    int p = blockIdx.x * BLOCK + tid;
    bool valid = p < P;
    float my_loc = 0.f; int my_pos = 0;
    if (valid) {
        float4 pr = ((const float4*)priors)[p];
        float px0 = pr.x - pr.z * 0.5f, py0 = pr.y - pr.w * 0.5f;
        float px1 = pr.x + pr.z * 0.5f, py1 = pr.y + pr.w * 0.5f;
        float areab = (px1 - px0) * (py1 - py0);

        float best = -1.f; int bo = 0;
        for (int o = 0; o < O; ++o) {
            float ltx = fmaxf(sbx[o*4+0], px0);
            float lty = fmaxf(sbx[o*4+1], py0);
            float rbx = fminf(sbx[o*4+2], px1);
            float rby = fminf(sbx[o*4+3], py1);
            float wx = fmaxf(rbx - ltx, 0.f), wy = fmaxf(rby - lty, 0.f);
            float inter = wx * wy;
            float iou = inter / (sarea[o] + areab - inter);
            if (iou > best) { best = iou; bo = o; }
        }
        int fo = -1;
        for (int o = 0; o < O; ++o) if (spf[o] == p) fo = o;
        int obj; float ov;
        if (fo >= 0) { obj = fo; ov = 1.0f; }
        else         { obj = bo; ov = best; }
        int lab = slab[obj];
        int tc = (ov < 0.5f) ? 0 : lab;
        tcarr[(size_t)n * P + p] = tc;
        if (tc != 0) {
            my_pos = 1;
            float x0 = sbx[obj*4+0], y0 = sbx[obj*4+1], x1 = sbx[obj*4+2], y1 = sbx[obj*4+3];
            float cx = (x0 + x1) * 0.5f, cy = (y0 + y1) * 0.5f;
            float w = x1 - x0, h = y1 - y0;
            float g0 = (cx - pr.x) / (pr.z / 10.0f);
            float g1 = (cy - pr.y) / (pr.w / 10.0f);
            float g2 = logf(w / pr.z) * 5.0f;
            float g3 = logf(h / pr.w) * 5.0f;
            const float* pl = locs + ((size_t)n * P + p) * 4;
            my_loc = fabsf(pl[0]-g0) + fabsf(pl[1]-g1) + fabsf(pl[2]-g2) + fabsf(pl[3]-g3);
        }
    }
    #pragma unroll
    for (int off = 32; off >= 1; off >>= 1) {
        my_loc += __shfl_down(my_loc, off);
        my_pos += __shfl_down(my_pos, off);
    }
    if ((tid & 63) == 0 && my_pos) {
        atomicAdd(&acc[0], my_loc);
        atomicAdd(&n_pos[n], my_pos);
    }
}

// ---------------- generic fallback (any C) ----------------
__global__ void loss_generic_kernel(const float* __restrict__ scores,
                                    const int* __restrict__ tcarr,
                                    float* __restrict__ ce_neg, float* __restrict__ acc,
                                    int NP, int C) {
    int t = blockIdx.x * blockDim.x + threadIdx.x;
    if (t >= NP) return;
    int tc = tcarr[t];
    const float* s = scores + (size_t)t * C;
    float m = -3.0e38f;
    for (int j = 0; j < C; ++j) m = fmaxf(m, s[j]);
    float l = 0.f, stc = 0.f;
    for (int j = 0; j < C; ++j) {
        float v = s[j];
        l += __expf(v - m);
        if (j == tc) stc = v;
    }
    float ce = m + logf(l) - stc;
    bool pos = (tc != 0);
    ce_neg[t] = pos ? 0.f : ce;
    if (pos) atomicAdd(&acc[1], ce);
}

// ---------------- K4: top-k sum per row + fused final combine ----------------
__global__ void topk_final_kernel(const float* __restrict__ ce_neg,
                                  const int* __restrict__ n_pos,
                                  float* __restrict__ acc, unsigned* __restrict__ done,
                                  int N, int P, unsigned* __restrict__ out) {
    __shared__ unsigned skeys[8732];
    __shared__ int hist[4096];        // aliased as ckeys later
    __shared__ int part[1024];
    __shared__ int s_tb, s_ca, s_tb2, s_ca2, s_cnt;
    __shared__ float shf[16];
    int n = blockIdx.x, tid = threadIdx.x;
    int k = 3 * n_pos[n]; if (k > P) k = P;
    float bsum = 0.f;

    if (k > 0) {                                      // block-uniform
        const float* row = ce_neg + (size_t)n * P;
        for (int i = tid; i < P; i += TK_THREADS) skeys[i] = __float_as_uint(row[i]);
        #pragma unroll
        for (int b = 0; b < 4; ++b) hist[tid * 4 + b] = 0;
        __syncthreads();

        for (int i = tid; i < P; i += TK_THREADS) atomicAdd(&hist[skeys[i] >> 20], 1);
        __syncthreads();
        int h0 = hist[tid*4], h1 = hist[tid*4+1], h2 = hist[tid*4+2], h3 = hist[tid*4+3];
        part[tid] = h0 + h1 + h2 + h3;
        __syncthreads();
        for (int s = 1; s < 1024; s <<= 1) {
            int v = part[tid] + ((tid + s < 1024) ? part[tid + s] : 0);
            __syncthreads();
            part[tid] = v;
            __syncthreads();
        }
        int sfx = (tid + 1 < 1024) ? part[tid + 1] : 0;
        int sf3 = sfx, sf2 = sfx + h3, sf1 = sf2 + h2, sf0 = sf1 + h1;
        if (sf0 < k && k <= sf0 + h0) { s_tb = tid*4;   s_ca = sf0; }
        if (sf1 < k && k <= sf1 + h1) { s_tb = tid*4+1; s_ca = sf1; }
        if (sf2 < k && k <= sf2 + h2) { s_tb = tid*4+2; s_ca = sf2; }
        if (sf3 < k && k <= sf3 + h3) { s_tb = tid*4+3; s_ca = sf3; }
        __syncthreads();
        int tb = s_tb, kk = k - s_ca;

        if (tid < 256) part[tid] = 0;
        __syncthreads();
        float ssum = 0.f;
        for (int i = tid; i < P; i += TK_THREADS) {
            unsigned key = skeys[i];
            int bin = key >> 20;
            if (bin > tb) ssum += __uint_as_float(key);
            else if (bin == tb) atomicAdd(&part[(key >> 12) & 255u], 1);
        }
        __syncthreads();
        if (tid < 256) {
            int cum = 0;
            for (int b = tid + 1; b < 256; ++b) cum += part[b];
            int h = part[tid];
            if (cum < kk && kk <= cum + h) { s_tb2 = tid; s_ca2 = cum; }
        }
        if (tid == 0) s_cnt = 0;
        __syncthreads();
        int tb2 = s_tb2, kk2 = kk - s_ca2;

        unsigned* ckeys = (unsigned*)hist;
        for (int i = tid; i < P; i += TK_THREADS) {
            unsigned key = skeys[i];
            if ((int)(key >> 20) == tb) {
                int b2 = (key >> 12) & 255u;
                if (b2 > tb2) ssum += __uint_as_float(key);
                else if (b2 == tb2) {
                    int slot = atomicAdd(&s_cnt, 1);
                    if (slot < CK_MAX) ckeys[slot] = key;
                }
            }
        }
        __syncthreads();
        int m = s_cnt; if (m > CK_MAX) m = CK_MAX;
        for (int i = tid; i < m; i += TK_THREADS) {
            unsigned key = ckeys[i];
            int rank = 0;
            for (int j = 0; j < m; ++j) {
                unsigned kj = ckeys[j];
                rank += (kj > key) || (kj == key && j < i);
            }
            if (rank < kk2) ssum += __uint_as_float(key);
        }
        #pragma unroll
        for (int off = 32; off >= 1; off >>= 1) ssum += __shfl_down(ssum, off);
        __syncthreads();
        if ((tid & 63) == 0) shf[tid >> 6] = ssum;
        __syncthreads();
        float tot = 0.f;
        for (int i = 0; i < 16; ++i) tot += shf[i];
        bsum = tot;
    }

    if (tid == 0) {
        if (bsum != 0.f) atomicAdd(&acc[2], bsum);
        __threadfence();                              // release our acc[2] add
        unsigned old = atomicAdd(done, 1u);
        if (old == (unsigned)(N - 1)) {               // last block: finalize
            float a0 = atomicAdd(&acc[0], 0.f);       // atomic reads (acquire-ish)
            float a1 = atomicAdd(&acc[1], 0.f);
            float a2 = atomicAdd(&acc[2], 0.f);
            int tot = 0;
            for (int i = 0; i < N; ++i) tot += n_pos[i];
            float npos = (float)tot;
            float conf = (a2 + a1) / npos;
            float loc  = a0 / (4.f * npos);
            float loss = conf + loc;
            unsigned ub = __float_as_uint(loss);
            unsigned r = (ub + 0x7FFFu + ((ub >> 16) & 1u)) >> 16;  // bf16 RNE
            out[0] = (r << 16) | r;
        }
    }
}

extern "C" void kernel_launch(void* const* d_in, const int* in_sizes, int n_in,
                              void* d_out, int out_size, void* d_ws, size_t ws_size,
                              hipStream_t stream) {
    const float* locs   = (const float*)d_in[0];
    const float* scores = (const float*)d_in[1];
    const float* boxes  = (const float*)d_in[2];
    const int*   labels = (const int*)d_in[3];
    const float* priors = (const float*)d_in[4];

    int P = in_sizes[4] / 4;
    long long NPl = in_sizes[0] / 4;
    int N = (int)(NPl / P);
    int C = (int)((long long)in_sizes[1] / NPl);
    int O = in_sizes[3] / N;
    size_t NP = (size_t)N * P;

    char* ws = (char*)d_ws;
    float*    acc   = (float*)ws;     ws += 16;
    unsigned* done  = (unsigned*)ws;  ws += 16;
    int*      n_pos = (int*)ws;       ws += (size_t)N * 4;
    int*      pfop  = (int*)ws;       ws += (size_t)N * O * 4;
    int*      tcarr = (int*)ws;       ws += NP * 4;
    float*    ce_neg= (float*)ws;     ws += NP * 4;

    match_object_kernel<<<N * O, BLOCK, 0, stream>>>(boxes, priors, pfop, acc, n_pos,
                                                     done, N, P, O);
    int gx = (P + BLOCK - 1) / BLOCK;
    if (C == 81 && (P % 4) == 0 && O <= MAXO) {
        fused_match_ce_kernel<<<dim3(gx, N), BLOCK, 0, stream>>>(
            boxes, priors, locs, labels, pfop, scores, ce_neg, acc, n_pos, N, P, O);
    } else {
        match_prior_kernel<<<dim3(gx, N), BLOCK, 0, stream>>>(boxes, priors, locs, labels,
                                                              pfop, tcarr, acc, n_pos, N, P, O);
        loss_generic_kernel<<<(int)((NP + BLOCK - 1) / BLOCK), BLOCK, 0, stream>>>(
            scores, tcarr, ce_neg, acc, (int)NP, C);
    }
    topk_final_kernel<<<N, TK_THREADS, 0, stream>>>(ce_neg, n_pos, acc, done, N, P,
                                                    (unsigned*)d_out);
}

// Round 6
// 226.870 us; speedup vs baseline: 1.2050x; 1.2050x over previous
//
#include <hip/hip_runtime.h>
#include <hip/hip_bf16.h>
#include <stdint.h>

#define BLOCK 256
#define MAXO 64
#define TK_THREADS 1024
#define CK_MAX 4096
#define RBPI 64            // row-wave kernel: blocks per image (64 x 4 waves = 256 waves/image)

// ---------------- K1: per-object argmax over P (block per (n,o)) + init ----------------
__global__ void match_object_kernel(const float* __restrict__ boxes,
                                    const float* __restrict__ priors,
                                    int* __restrict__ pfop,
                                    float* __restrict__ acc, int* __restrict__ n_pos,
                                    unsigned* __restrict__ done, int N, int P, int O) {
    __shared__ unsigned long long swm[4];
    int idx = blockIdx.x, tid = threadIdx.x;
    if (idx == 0) {                       // init for later dispatches (stream-ordered)
        for (int j = tid; j < N; j += BLOCK) n_pos[j] = 0;
        if (tid >= 64 && tid < 67) acc[tid - 64] = 0.f;
        if (tid == 96) *done = 0u;
    }
    const float* b = boxes + (size_t)idx * 4;
    float bx0 = b[0], by0 = b[1], bx1 = b[2], by1 = b[3];
    float areaa = (bx1 - bx0) * (by1 - by0);

    unsigned long long best = 0ULL;
    for (int p = tid; p < P; p += BLOCK) {
        float4 pr = ((const float4*)priors)[p];
        float px0 = pr.x - pr.z * 0.5f, py0 = pr.y - pr.w * 0.5f;
        float px1 = pr.x + pr.z * 0.5f, py1 = pr.y + pr.w * 0.5f;
        float areab = (px1 - px0) * (py1 - py0);
        float ltx = fmaxf(bx0, px0), lty = fmaxf(by0, py0);
        float rbx = fminf(bx1, px1), rby = fminf(by1, py1);
        float wx = fmaxf(rbx - ltx, 0.f), wy = fmaxf(rby - lty, 0.f);
        float inter = wx * wy;
        float iou = inter / (areaa + areab - inter);
        unsigned long long cand = (((unsigned long long)__float_as_uint(iou)) << 32) |
                                  (unsigned long long)(0xFFFFFFFFu - (unsigned)p);
        if (cand > best) best = cand;     // larger iou; tie -> smaller p (numpy first)
    }
    #pragma unroll
    for (int off = 32; off >= 1; off >>= 1) {
        unsigned long long other = __shfl_down(best, off);
        if (other > best) best = other;
    }
    if ((tid & 63) == 0) swm[tid >> 6] = best;
    __syncthreads();
    if (tid == 0) {
        unsigned long long r = swm[0];
        for (int w = 1; w < BLOCK / 64; ++w) if (swm[w] > r) r = swm[w];
        pfop[idx] = (int)(0xFFFFFFFFu - (unsigned)(r & 0xFFFFFFFFull));
    }
}

// ---------------- K2+K3 fused v6: one WAVE per score row, dense streaming ----------------
// Five rounds of evidence: the 16B-granule quad gather (64 scattered lines/instr) at
// ~8 waves/CU is latency-bound at ~6.6 KB/us/CU regardless of load scheduling (compiler
// dribble 54us; DMA convoy 81-90us; asm burst spilled 132us). v6 adopts the pattern this
// machine demonstrably streams at 6.5 TB/s (fill kernel): lane-linear contiguous dwords.
// Wave handles row t: lane i reads row[i], lane<17 reads row[64+i] -> 324B contiguous,
// 2 load instrs. Match distributes over lanes (lane o = object o, O<=64): IoU in
// parallel, packed-u64 xor-reduce argmax, ballot+clz forced-match. stc via shuffle of
// the already-loaded row (zero extra loads). No LDS in hot loop, no atomics anywhere:
// per-block partials (plain stores) reduced later by topk.
__global__ void __launch_bounds__(BLOCK)
fused_rowwave_kernel(const float* __restrict__ boxes,
                     const float* __restrict__ priors,
                     const float* __restrict__ locs,
                     const int* __restrict__ labels,
                     const int* __restrict__ pfop,
                     const float* __restrict__ scores,
                     float* __restrict__ ce_neg,
                     float* __restrict__ pb_loc, float* __restrict__ pb_pce,
                     int* __restrict__ pb_npos,
                     int N, int P, int O) {
    int n = blockIdx.y, bx = blockIdx.x, tid = threadIdx.x;
    int w = tid >> 6, lane = tid & 63;
    int wid = bx * 4 + w;                 // wave id within image
    const int WPI = RBPI * 4;             // waves per image

    // per-image metadata in registers: lane o holds object o
    float4 box = make_float4(0.f, 0.f, 0.f, 0.f);
    int lab = 0, pf = -1;
    if (lane < O) {
        box = ((const float4*)boxes)[n * O + lane];
        lab = labels[n * O + lane];
        pf  = pfop[n * O + lane];
    }

    float wloc = 0.f, wpce = 0.f; int wnp = 0;
    for (int p = wid; p < P; p += WPI) {
        size_t t = (size_t)n * P + p;
        const float* base = scores + t * 81;
        float x1 = base[lane];                         // 256B lane-linear
        bool has2 = lane < 17;
        float x2 = has2 ? base[64 + lane] : 0.f;       // 68B tail (exec-masked, in-bounds)
        float4 pr = ((const float4*)priors)[p];        // same-address broadcast load

        // ---- softmax denominator: 81 exps across the wave, xor-tree reduce ----
        float e = __expf(x1) + (has2 ? __expf(x2) : 0.f);
        #pragma unroll
        for (int off = 32; off >= 1; off >>= 1) e += __shfl_xor(e, off);

        // ---- match: lane o computes IoU(object o, prior p) ----
        float px0 = pr.x - pr.z * 0.5f, py0 = pr.y - pr.w * 0.5f;
        float px1v = pr.x + pr.z * 0.5f, py1v = pr.y + pr.w * 0.5f;
        float areab = (px1v - px0) * (py1v - py0);
        unsigned long long key = 0ULL;
        if (lane < O) {
            float ltx = fmaxf(box.x, px0), lty = fmaxf(box.y, py0);
            float rbx = fminf(box.z, px1v), rby = fminf(box.w, py1v);
            float wx = fmaxf(rbx - ltx, 0.f), wy = fmaxf(rby - lty, 0.f);
            float inter = wx * wy;
            float areao = (box.z - box.x) * (box.w - box.y);
            float iou = inter / (areao + areab - inter);
            key = (((unsigned long long)__float_as_uint(iou)) << 32) |
                  (unsigned long long)(0xFFFFFFFFu - (unsigned)lane);   // tie -> smaller o
        }
        #pragma unroll
        for (int off = 32; off >= 1; off >>= 1) {
            unsigned long long o2 = __shfl_xor(key, off);
            if (o2 > key) key = o2;
        }
        int obj = (int)(0xFFFFFFFFu - (unsigned)(key & 0xFFFFFFFFull));
        float ov = __uint_as_float((unsigned)(key >> 32));
        unsigned long long fm = __ballot(pf == p);     // forced match: last o wins
        if (fm) { obj = 63 - __builtin_clzll(fm); ov = 1.0f; }
        int tc = (ov < 0.5f) ? 0 : __shfl(lab, obj);   // wave-uniform

        // ---- CE: stc from the already-loaded row via shuffle ----
        float l = logf(e);
        float stc = (tc < 64) ? __shfl(x1, tc) : __shfl(x2, tc - 64);
        float ce = l - stc;
        bool pos = (tc != 0);                          // wave-uniform branch
        if (pos) {
            float bx0 = __shfl(box.x, obj), by0 = __shfl(box.y, obj);
            float bx1 = __shfl(box.z, obj), by1 = __shfl(box.w, obj);
            float4 pl = ((const float4*)locs)[t];      // broadcast load, rare
            float cx = (bx0 + bx1) * 0.5f, cy = (by0 + by1) * 0.5f;
            float bw = bx1 - bx0, bh = by1 - by0;
            float g0 = (cx - pr.x) / (pr.z / 10.0f);
            float g1 = (cy - pr.y) / (pr.w / 10.0f);
            float g2 = logf(bw / pr.z) * 5.0f;
            float g3 = logf(bh / pr.w) * 5.0f;
            if (lane == 0) {
                wloc += fabsf(pl.x-g0) + fabsf(pl.y-g1) + fabsf(pl.z-g2) + fabsf(pl.w-g3);
                wpce += ce;
                wnp  += 1;
            }
        }
        if (lane == 0) ce_neg[t] = pos ? 0.f : ce;
    }

    // block-level partials: plain stores, no atomics
    __shared__ float sl[4], sp[4]; __shared__ int sn[4];
    if (lane == 0) { sl[w] = wloc; sp[w] = wpce; sn[w] = wnp; }
    __syncthreads();
    if (tid == 0) {
        pb_loc[n * RBPI + bx]  = (sl[0] + sl[1]) + (sl[2] + sl[3]);
        pb_pce[n * RBPI + bx]  = (sp[0] + sp[1]) + (sp[2] + sp[3]);
        pb_npos[n * RBPI + bx] = sn[0] + sn[1] + sn[2] + sn[3];
    }
}

// ---------------- fallback K2: per-prior match -> tcarr (any C path) ----------------
__global__ void match_prior_kernel(const float* __restrict__ boxes,
                                   const float* __restrict__ priors,
                                   const float* __restrict__ locs,
                                   const int* __restrict__ labels,
                                   const int* __restrict__ pfop,
                                   int* __restrict__ tcarr,
                                   float* __restrict__ acc, int* __restrict__ n_pos,
                                   int N, int P, int O) {
    __shared__ float sbx[MAXO * 4];
    __shared__ float sarea[MAXO];
    __shared__ int   spf[MAXO];
    __shared__ int   slab[MAXO];
    int n = blockIdx.y, tid = threadIdx.x;
    if (tid < O * 4) sbx[tid] = boxes[(size_t)n * O * 4 + tid];
    if (tid >= 128 && tid < 128 + O) spf[tid - 128]  = pfop[n * O + (tid - 128)];
    if (tid >= 192 && tid < 192 + O) slab[tid - 192] = labels[n * O + (tid - 192)];
    __syncthreads();
    if (tid < O)
        sarea[tid] = (sbx[tid*4+2] - sbx[tid*4+0]) * (sbx[tid*4+3] - sbx[tid*4+1]);
    __syncthreads();

    int p = blockIdx.x * BLOCK + tid;
    bool valid = p < P;
    float my_loc = 0.f; int my_pos = 0;
    if (valid) {
        float4 pr = ((const float4*)priors)[p];
        float px0 = pr.x - pr.z * 0.5f, py0 = pr.y - pr.w * 0.5f;
        float px1 = pr.x + pr.z * 0.5f, py1 = pr.y + pr.w * 0.5f;
        float areab = (px1 - px0) * (py1 - py0);

        float best = -1.f; int bo = 0;
        for (int o = 0; o < O; ++o) {
            float ltx = fmaxf(sbx[o*4+0], px0);
            float lty = fmaxf(sbx[o*4+1], py0);
            float rbx = fminf(sbx[o*4+2], px1);
            float rby = fminf(sbx[o*4+3], py1);
            float wx = fmaxf(rbx - ltx, 0.f), wy = fmaxf(rby - lty, 0.f);
            float inter = wx * wy;
            float iou = inter / (sarea[o] + areab - inter);
            if (iou > best) { best = iou; bo = o; }
        }
        int fo = -1;
        for (int o = 0; o < O; ++o) if (spf[o] == p) fo = o;
        int obj; float ov;
        if (fo >= 0) { obj = fo; ov = 1.0f; }
        else         { obj = bo; ov = best; }
        int lab = slab[obj];
        int tc = (ov < 0.5f) ? 0 : lab;
        tcarr[(size_t)n * P + p] = tc;
        if (tc != 0) {
            my_pos = 1;
            float x0 = sbx[obj*4+0], y0 = sbx[obj*4+1], x1 = sbx[obj*4+2], y1 = sbx[obj*4+3];
            float cx = (x0 + x1) * 0.5f, cy = (y0 + y1) * 0.5f;
            float w = x1 - x0, h = y1 - y0;
            float g0 = (cx - pr.x) / (pr.z / 10.0f);
            float g1 = (cy - pr.y) / (pr.w / 10.0f);
            float g2 = logf(w / pr.z) * 5.0f;
            float g3 = logf(h / pr.w) * 5.0f;
            const float* pl = locs + ((size_t)n * P + p) * 4;
            my_loc = fabsf(pl[0]-g0) + fabsf(pl[1]-g1) + fabsf(pl[2]-g2) + fabsf(pl[3]-g3);
        }
    }
    #pragma unroll
    for (int off = 32; off >= 1; off >>= 1) {
        my_loc += __shfl_down(my_loc, off);
        my_pos += __shfl_down(my_pos, off);
    }
    if ((tid & 63) == 0 && my_pos) {
        atomicAdd(&acc[0], my_loc);
        atomicAdd(&n_pos[n], my_pos);
    }
}

// ---------------- generic fallback (any C) ----------------
__global__ void loss_generic_kernel(const float* __restrict__ scores,
                                    const int* __restrict__ tcarr,
                                    float* __restrict__ ce_neg, float* __restrict__ acc,
                                    int NP, int C) {
    int t = blockIdx.x * blockDim.x + threadIdx.x;
    if (t >= NP) return;
    int tc = tcarr[t];
    const float* s = scores + (size_t)t * C;
    float m = -3.0e38f;
    for (int j = 0; j < C; ++j) m = fmaxf(m, s[j]);
    float l = 0.f, stc = 0.f;
    for (int j = 0; j < C; ++j) {
        float v = s[j];
        l += __expf(v - m);
        if (j == tc) stc = v;
    }
    float ce = m + logf(l) - stc;
    bool pos = (tc != 0);
    ce_neg[t] = pos ? 0.f : ce;
    if (pos) atomicAdd(&acc[1], ce);
}

// ---------------- K4: top-k sum per row + partial-reduce + fused final combine ----------------
__global__ void topk_final_kernel(const float* __restrict__ ce_neg,
                                  int* __restrict__ n_pos,
                                  const float* __restrict__ pb_loc,
                                  const float* __restrict__ pb_pce,
                                  const int* __restrict__ pb_npos, int npb,
                                  float* __restrict__ acc, unsigned* __restrict__ done,
                                  int N, int P, unsigned* __restrict__ out) {
    __shared__ unsigned skeys[8732];
    __shared__ int hist[4096];        // aliased as ckeys later
    __shared__ int part[1024];
    __shared__ int s_tb, s_ca, s_tb2, s_ca2, s_cnt, s_np;
    __shared__ float shf[16];
    int n = blockIdx.x, tid = threadIdx.x;

    int k;
    if (npb > 0) {                    // fused path: reduce per-block partials (wave 0)
        if (tid < 64) {
            float psl = 0.f, psp = 0.f; int psn = 0;
            for (int i = tid; i < npb; i += 64) {
                psl += pb_loc[n * npb + i];
                psp += pb_pce[n * npb + i];
                psn += pb_npos[n * npb + i];
            }
            #pragma unroll
            for (int off = 32; off >= 1; off >>= 1) {
                psl += __shfl_down(psl, off);
                psp += __shfl_down(psp, off);
                psn += __shfl_down(psn, off);
            }
            if (tid == 0) {
                s_np = psn;
                n_pos[n] = psn;                       // plain store; fenced before done++
                if (psl != 0.f) atomicAdd(&acc[0], psl);
                if (psp != 0.f) atomicAdd(&acc[1], psp);
            }
        }
        __syncthreads();
        k = 3 * s_np;
    } else {
        k = 3 * n_pos[n];
    }
    if (k > P) k = P;
    float bsum = 0.f;

    if (k > 0) {                                      // block-uniform
        const float* row = ce_neg + (size_t)n * P;
        for (int i = tid; i < P; i += TK_THREADS) skeys[i] = __float_as_uint(row[i]);
        #pragma unroll
        for (int b = 0; b < 4; ++b) hist[tid * 4 + b] = 0;
        __syncthreads();

        for (int i = tid; i < P; i += TK_THREADS) atomicAdd(&hist[skeys[i] >> 20], 1);
        __syncthreads();
        int h0 = hist[tid*4], h1 = hist[tid*4+1], h2 = hist[tid*4+2], h3 = hist[tid*4+3];
        part[tid] = h0 + h1 + h2 + h3;
        __syncthreads();
        for (int s = 1; s < 1024; s <<= 1) {
            int v = part[tid] + ((tid + s < 1024) ? part[tid + s] : 0);
            __syncthreads();
            part[tid] = v;
            __syncthreads();
        }
        int sfx = (tid + 1 < 1024) ? part[tid + 1] : 0;
        int sf3 = sfx, sf2 = sfx + h3, sf1 = sf2 + h2, sf0 = sf1 + h1;
        if (sf0 < k && k <= sf0 + h0) { s_tb = tid*4;   s_ca = sf0; }
        if (sf1 < k && k <= sf1 + h1) { s_tb = tid*4+1; s_ca = sf1; }
        if (sf2 < k && k <= sf2 + h2) { s_tb = tid*4+2; s_ca = sf2; }
        if (sf3 < k && k <= sf3 + h3) { s_tb = tid*4+3; s_ca = sf3; }
        __syncthreads();
        int tb = s_tb, kk = k - s_ca;

        if (tid < 256) part[tid] = 0;
        __syncthreads();
        float ssum = 0.f;
        for (int i = tid; i < P; i += TK_THREADS) {
            unsigned key = skeys[i];
            int bin = key >> 20;
            if (bin > tb) ssum += __uint_as_float(key);
            else if (bin == tb) atomicAdd(&part[(key >> 12) & 255u], 1);
        }
        __syncthreads();
        if (tid < 256) {
            int cum = 0;
            for (int b = tid + 1; b < 256; ++b) cum += part[b];
            int h = part[tid];
            if (cum < kk && kk <= cum + h) { s_tb2 = tid; s_ca2 = cum; }
        }
        if (tid == 0) s_cnt = 0;
        __syncthreads();
        int tb2 = s_tb2, kk2 = kk - s_ca2;

        unsigned* ckeys = (unsigned*)hist;
        for (int i = tid; i < P; i += TK_THREADS) {
            unsigned key = skeys[i];
            if ((int)(key >> 20) == tb) {
                int b2 = (key >> 12) & 255u;
                if (b2 > tb2) ssum += __uint_as_float(key);
                else if (b2 == tb2) {
                    int slot = atomicAdd(&s_cnt, 1);
                    if (slot < CK_MAX) ckeys[slot] = key;
                }
            }
        }
        __syncthreads();
        int m = s_cnt; if (m > CK_MAX) m = CK_MAX;
        for (int i = tid; i < m; i += TK_THREADS) {
            unsigned key = ckeys[i];
            int rank = 0;
            for (int j = 0; j < m; ++j) {
                unsigned kj = ckeys[j];
                rank += (kj > key) || (kj == key && j < i);
            }
            if (rank < kk2) ssum += __uint_as_float(key);
        }
        #pragma unroll
        for (int off = 32; off >= 1; off >>= 1) ssum += __shfl_down(ssum, off);
        __syncthreads();
        if ((tid & 63) == 0) shf[tid >> 6] = ssum;
        __syncthreads();
        float tot = 0.f;
        for (int i = 0; i < 16; ++i) tot += shf[i];
        bsum = tot;
    }

    if (tid == 0) {
        if (bsum != 0.f) atomicAdd(&acc[2], bsum);
        __threadfence();                              // release acc adds + n_pos store
        unsigned old = atomicAdd(done, 1u);
        if (old == (unsigned)(N - 1)) {               // last block: finalize
            float a0 = atomicAdd(&acc[0], 0.f);       // atomic reads (acquire-ish)
            float a1 = atomicAdd(&acc[1], 0.f);
            float a2 = atomicAdd(&acc[2], 0.f);
            int tot = 0;
            for (int i = 0; i < N; ++i) tot += n_pos[i];
            float npos = (float)tot;
            float conf = (a2 + a1) / npos;
            float loc  = a0 / (4.f * npos);
            float loss = conf + loc;
            unsigned ub = __float_as_uint(loss);
            unsigned r = (ub + 0x7FFFu + ((ub >> 16) & 1u)) >> 16;  // bf16 RNE
            out[0] = (r << 16) | r;
        }
    }
}

extern "C" void kernel_launch(void* const* d_in, const int* in_sizes, int n_in,
                              void* d_out, int out_size, void* d_ws, size_t ws_size,
                              hipStream_t stream) {
    const float* locs   = (const float*)d_in[0];
    const float* scores = (const float*)d_in[1];
    const float* boxes  = (const float*)d_in[2];
    const int*   labels = (const int*)d_in[3];
    const float* priors = (const float*)d_in[4];

    int P = in_sizes[4] / 4;
    long long NPl = in_sizes[0] / 4;
    int N = (int)(NPl / P);
    int C = (int)((long long)in_sizes[1] / NPl);
    int O = in_sizes[3] / N;
    size_t NP = (size_t)N * P;

    char* ws = (char*)d_ws;
    float*    acc    = (float*)ws;     ws += 16;
    unsigned* done   = (unsigned*)ws;  ws += 16;
    int*      n_pos  = (int*)ws;       ws += (size_t)N * 4;
    int*      pfop   = (int*)ws;       ws += (size_t)N * O * 4;
    float*    pb_loc = (float*)ws;     ws += (size_t)N * RBPI * 4;
    float*    pb_pce = (float*)ws;     ws += (size_t)N * RBPI * 4;
    int*      pb_npos= (int*)ws;       ws += (size_t)N * RBPI * 4;
    int*      tcarr  = (int*)ws;       ws += NP * 4;
    float*    ce_neg = (float*)ws;     ws += NP * 4;

    match_object_kernel<<<N * O, BLOCK, 0, stream>>>(boxes, priors, pfop, acc, n_pos,
                                                     done, N, P, O);
    int npb = 0;
    if (C == 81 && O <= 64) {
        npb = RBPI;
        fused_rowwave_kernel<<<dim3(RBPI, N), BLOCK, 0, stream>>>(
            boxes, priors, locs, labels, pfop, scores, ce_neg,
            pb_loc, pb_pce, pb_npos, N, P, O);
    } else {
        int gx = (P + BLOCK - 1) / BLOCK;
        match_prior_kernel<<<dim3(gx, N), BLOCK, 0, stream>>>(boxes, priors, locs, labels,
                                                              pfop, tcarr, acc, n_pos, N, P, O);
        loss_generic_kernel<<<(int)((NP + BLOCK - 1) / BLOCK), BLOCK, 0, stream>>>(
            scores, tcarr, ce_neg, acc, (int)NP, C);
    }
    topk_final_kernel<<<N, TK_THREADS, 0, stream>>>(ce_neg, n_pos,
                                                    pb_loc, pb_pce, pb_npos, npb,
                                                    acc, done, N, P, (unsigned*)d_out);
}

// Round 7
// 182.592 us; speedup vs baseline: 1.4973x; 1.2425x over previous
//
#include <hip/hip_runtime.h>
#include <hip/hip_bf16.h>
#include <stdint.h>

#define BLOCK 256
#define SBLOCK 128
#define MAXO 64
#define TK_THREADS 1024
#define CK_MAX 4096

// ---------------- K1: per-object argmax over P (block per (n,o)) + init ----------------
__global__ void match_object_kernel(const float* __restrict__ boxes,
                                    const float* __restrict__ priors,
                                    int* __restrict__ pfop,
                                    float* __restrict__ acc, int* __restrict__ n_pos,
                                    unsigned* __restrict__ done, int N, int P, int O) {
    __shared__ unsigned long long swm[4];
    int idx = blockIdx.x, tid = threadIdx.x;
    if (idx == 0) {                       // init for later dispatches (stream-ordered)
        for (int j = tid; j < N; j += BLOCK) n_pos[j] = 0;
        if (tid >= 64 && tid < 67) acc[tid - 64] = 0.f;
        if (tid == 96) *done = 0u;
    }
    const float* b = boxes + (size_t)idx * 4;
    float bx0 = b[0], by0 = b[1], bx1 = b[2], by1 = b[3];
    float areaa = (bx1 - bx0) * (by1 - by0);

    unsigned long long best = 0ULL;
    for (int p = tid; p < P; p += BLOCK) {
        float4 pr = ((const float4*)priors)[p];
        float px0 = pr.x - pr.z * 0.5f, py0 = pr.y - pr.w * 0.5f;
        float px1 = pr.x + pr.z * 0.5f, py1 = pr.y + pr.w * 0.5f;
        float areab = (px1 - px0) * (py1 - py0);
        float ltx = fmaxf(bx0, px0), lty = fmaxf(by0, py0);
        float rbx = fminf(bx1, px1), rby = fminf(by1, py1);
        float wx = fmaxf(rbx - ltx, 0.f), wy = fmaxf(rby - lty, 0.f);
        float inter = wx * wy;
        float iou = inter / (areaa + areab - inter);
        unsigned long long cand = (((unsigned long long)__float_as_uint(iou)) << 32) |
                                  (unsigned long long)(0xFFFFFFFFu - (unsigned)p);
        if (cand > best) best = cand;     // larger iou; tie -> smaller p (numpy first)
    }
    #pragma unroll
    for (int off = 32; off >= 1; off >>= 1) {
        unsigned long long other = __shfl_down(best, off);
        if (other > best) best = other;
    }
    if ((tid & 63) == 0) swm[tid >> 6] = best;
    __syncthreads();
    if (tid == 0) {
        unsigned long long r = swm[0];
        for (int w = 1; w < BLOCK / 64; ++w) if (swm[w] > r) r = swm[w];
        pfop[idx] = (int)(0xFFFFFFFFu - (unsigned)(r & 0xFFFFFFFFull));
    }
}

// ---------------- K2+K3 fused v7: LDS-bounce staging, thread-per-row consume ----------------
// Six rounds of evidence: strided thread-per-row gather = latency-bound (54us);
// wave-per-row dense = VALU-bound on reduction scaffolding (88us, VALUBusy 54%).
// v7: the 128-row chunk is CONTIGUOUS row-major [128][81] -> stage it to LDS with a
// trivial coalesced float4 copy (identity layout, plain reg-staged loads -- the one
// streaming pattern this machine runs at full rate), then each thread consumes its
// own row from LDS: 81 ds_read_b32 at bank stride 17 (2 lanes/bank = free, m136),
// 81 exps, v2-style match from LDS metadata, stc free from the staged row.
// No atomics in hot path: per-block partials reduced in topk (v6 mechanism kept).
__global__ void __launch_bounds__(SBLOCK)
fused_staged_kernel(const float* __restrict__ boxes,
                    const float* __restrict__ priors,
                    const float* __restrict__ locs,
                    const int* __restrict__ labels,
                    const int* __restrict__ pfop,
                    const float* __restrict__ scores,
                    float* __restrict__ ce_neg,
                    float* __restrict__ pb_loc, float* __restrict__ pb_pce,
                    int* __restrict__ pb_npos,
                    int N, int P, int O) {
    __shared__ float4 sstage4[SBLOCK * 81 / 4];   // 2592 float4 = 41,472 B
    __shared__ float sbx[MAXO * 4];
    __shared__ int   spf[MAXO];
    __shared__ int   slab[MAXO];
    __shared__ float sl[2], sp[2]; __shared__ int sn[2];
    const float* sstage = (const float*)sstage4;

    int n = blockIdx.y, bx = blockIdx.x, tid = threadIdx.x;
    int w = tid >> 6, lane = tid & 63;
    int p0 = bx * SBLOCK;
    int rows = P - p0; if (rows > SBLOCK) rows = SBLOCK;   // rows % 4 == 0 (P % 4 == 0)
    int p = p0 + tid;
    bool valid = tid < rows;
    size_t t = (size_t)n * P + p;

    // ---- metadata -> LDS (small), prior/loc -> regs ----
    for (int i = tid; i < O * 4; i += SBLOCK) sbx[i] = boxes[(size_t)n * O * 4 + i];
    for (int i = tid; i < O; i += SBLOCK) { spf[i] = pfop[n * O + i]; slab[i] = labels[n * O + i]; }
    float4 pr = make_float4(0.f, 0.f, 1.f, 1.f);
    float4 pl = make_float4(0.f, 0.f, 0.f, 0.f);
    if (valid) {
        pr = ((const float4*)priors)[p];
        pl = ((const float4*)locs)[t];
    }

    // ---- stage: coalesced float4 copy, identity layout (global chunk is contiguous) ----
    const float4* chunk = (const float4*)(scores + ((size_t)n * P + p0) * 81);
    if (rows == SBLOCK) {
        #pragma unroll
        for (int j = 0; j < 20; ++j)
            sstage4[j * SBLOCK + tid] = chunk[j * SBLOCK + tid];
        if (tid < 32)                                  // tail: 2560..2591
            sstage4[20 * SBLOCK + tid] = chunk[20 * SBLOCK + tid];
    } else {                                           // partial tile (one per image)
        int nf4 = rows * 81 / 4;
        for (int j = 0; j < 21; ++j) {
            int idx = j * SBLOCK + tid;
            if (idx < nf4) sstage4[idx] = chunk[idx];
        }
    }
    __syncthreads();

    // ---- consume: thread-per-row from LDS ----
    float my_loc = 0.f, my_pce = 0.f; int my_pos = 0;
    if (valid) {
        const float* row = sstage + tid * 81;          // bank stride 17: conflict-free
        float e = 0.f;
        #pragma unroll
        for (int j = 0; j < 81; ++j) e += __expf(row[j]);

        // match (v2 semantics): strict > = first index; forced match last-wins
        float px0 = pr.x - pr.z * 0.5f, py0 = pr.y - pr.w * 0.5f;
        float px1 = pr.x + pr.z * 0.5f, py1 = pr.y + pr.w * 0.5f;
        float areab = (px1 - px0) * (py1 - py0);
        float best = -1.f; int bo = 0;
        for (int o = 0; o < O; ++o) {                  // sbx reads wave-broadcast
            float x0 = sbx[o*4+0], y0 = sbx[o*4+1], x1 = sbx[o*4+2], y1 = sbx[o*4+3];
            float ltx = fmaxf(x0, px0), lty = fmaxf(y0, py0);
            float rbx = fminf(x1, px1), rby = fminf(y1, py1);
            float wx = fmaxf(rbx - ltx, 0.f), wy = fmaxf(rby - lty, 0.f);
            float inter = wx * wy;
            float areao = (x1 - x0) * (y1 - y0);
            float iou = inter / (areao + areab - inter);
            if (iou > best) { best = iou; bo = o; }
        }
        int fo = -1;
        for (int o = 0; o < O; ++o) if (spf[o] == p) fo = o;
        int obj; float ov;
        if (fo >= 0) { obj = fo; ov = 1.0f; }
        else         { obj = bo; ov = best; }
        int tc = (ov < 0.5f) ? 0 : slab[obj];

        float stc = row[tc];                           // free: already staged
        float ce = logf(e) - stc;
        bool pos = (tc != 0);
        ce_neg[t] = pos ? 0.f : ce;                    // coalesced store
        if (pos) {
            my_pce = ce; my_pos = 1;
            float x0 = sbx[obj*4+0], y0 = sbx[obj*4+1], x1 = sbx[obj*4+2], y1 = sbx[obj*4+3];
            float cx = (x0 + x1) * 0.5f, cy = (y0 + y1) * 0.5f;
            float bw = x1 - x0, bh = y1 - y0;
            float g0 = (cx - pr.x) / (pr.z / 10.0f);
            float g1 = (cy - pr.y) / (pr.w / 10.0f);
            float g2 = logf(bw / pr.z) * 5.0f;
            float g3 = logf(bh / pr.w) * 5.0f;
            my_loc = fabsf(pl.x-g0) + fabsf(pl.y-g1) + fabsf(pl.z-g2) + fabsf(pl.w-g3);
        }
    }

    // ---- block partials: plain stores, no atomics ----
    #pragma unroll
    for (int off = 32; off >= 1; off >>= 1) {
        my_loc += __shfl_down(my_loc, off);
        my_pce += __shfl_down(my_pce, off);
        my_pos += __shfl_down(my_pos, off);
    }
    if (lane == 0) { sl[w] = my_loc; sp[w] = my_pce; sn[w] = my_pos; }
    __syncthreads();
    if (tid == 0) {
        int npb = gridDim.x;
        pb_loc[n * npb + bx]  = sl[0] + sl[1];
        pb_pce[n * npb + bx]  = sp[0] + sp[1];
        pb_npos[n * npb + bx] = sn[0] + sn[1];
    }
}

// ---------------- fallback K2: per-prior match -> tcarr (any C path) ----------------
__global__ void match_prior_kernel(const float* __restrict__ boxes,
                                   const float* __restrict__ priors,
                                   const float* __restrict__ locs,
                                   const int* __restrict__ labels,
                                   const int* __restrict__ pfop,
                                   int* __restrict__ tcarr,
                                   float* __restrict__ acc, int* __restrict__ n_pos,
                                   int N, int P, int O) {
    __shared__ float sbx[MAXO * 4];
    __shared__ float sarea[MAXO];
    __shared__ int   spf[MAXO];
    __shared__ int   slab[MAXO];
    int n = blockIdx.y, tid = threadIdx.x;
    if (tid < O * 4) sbx[tid] = boxes[(size_t)n * O * 4 + tid];
    if (tid >= 128 && tid < 128 + O) spf[tid - 128]  = pfop[n * O + (tid - 128)];
    if (tid >= 192 && tid < 192 + O) slab[tid - 192] = labels[n * O + (tid - 192)];
    __syncthreads();
    if (tid < O)
        sarea[tid] = (sbx[tid*4+2] - sbx[tid*4+0]) * (sbx[tid*4+3] - sbx[tid*4+1]);
    __syncthreads();

    int p = blockIdx.x * BLOCK + tid;
    bool valid = p < P;
    float my_loc = 0.f; int my_pos = 0;
    if (valid) {
        float4 pr = ((const float4*)priors)[p];
        float px0 = pr.x - pr.z * 0.5f, py0 = pr.y - pr.w * 0.5f;
        float px1 = pr.x + pr.z * 0.5f, py1 = pr.y + pr.w * 0.5f;
        float areab = (px1 - px0) * (py1 - py0);

        float best = -1.f; int bo = 0;
        for (int o = 0; o < O; ++o) {
            float ltx = fmaxf(sbx[o*4+0], px0);
            float lty = fmaxf(sbx[o*4+1], py0);
            float rbx = fminf(sbx[o*4+2], px1);
            float rby = fminf(sbx[o*4+3], py1);
            float wx = fmaxf(rbx - ltx, 0.f), wy = fmaxf(rby - lty, 0.f);
            float inter = wx * wy;
            float iou = inter / (sarea[o] + areab - inter);
            if (iou > best) { best = iou; bo = o; }
        }
        int fo = -1;
        for (int o = 0; o < O; ++o) if (spf[o] == p) fo = o;
        int obj; float ov;
        if (fo >= 0) { obj = fo; ov = 1.0f; }
        else         { obj = bo; ov = best; }
        int lab = slab[obj];
        int tc = (ov < 0.5f) ? 0 : lab;
        tcarr[(size_t)n * P + p] = tc;
        if (tc != 0) {
            my_pos = 1;
            float x0 = sbx[obj*4+0], y0 = sbx[obj*4+1], x1 = sbx[obj*4+2], y1 = sbx[obj*4+3];
            float cx = (x0 + x1) * 0.5f, cy = (y0 + y1) * 0.5f;
            float w = x1 - x0, h = y1 - y0;
            float g0 = (cx - pr.x) / (pr.z / 10.0f);
            float g1 = (cy - pr.y) / (pr.w / 10.0f);
            float g2 = logf(w / pr.z) * 5.0f;
            float g3 = logf(h / pr.w) * 5.0f;
            const float* pl = locs + ((size_t)n * P + p) * 4;
            my_loc = fabsf(pl[0]-g0) + fabsf(pl[1]-g1) + fabsf(pl[2]-g2) + fabsf(pl[3]-g3);
        }
    }
    #pragma unroll
    for (int off = 32; off >= 1; off >>= 1) {
        my_loc += __shfl_down(my_loc, off);
        my_pos += __shfl_down(my_pos, off);
    }
    if ((tid & 63) == 0 && my_pos) {
        atomicAdd(&acc[0], my_loc);
        atomicAdd(&n_pos[n], my_pos);
    }
}

// ---------------- generic fallback (any C) ----------------
__global__ void loss_generic_kernel(const float* __restrict__ scores,
                                    const int* __restrict__ tcarr,
                                    float* __restrict__ ce_neg, float* __restrict__ acc,
                                    int NP, int C) {
    int t = blockIdx.x * blockDim.x + threadIdx.x;
    if (t >= NP) return;
    int tc = tcarr[t];
    const float* s = scores + (size_t)t * C;
    float m = -3.0e38f;
    for (int j = 0; j < C; ++j) m = fmaxf(m, s[j]);
    float l = 0.f, stc = 0.f;
    for (int j = 0; j < C; ++j) {
        float v = s[j];
        l += __expf(v - m);
        if (j == tc) stc = v;
    }
    float ce = m + logf(l) - stc;
    bool pos = (tc != 0);
    ce_neg[t] = pos ? 0.f : ce;
    if (pos) atomicAdd(&acc[1], ce);
}

// ---------------- K4: top-k sum per row + partial-reduce + fused final combine ----------------
__global__ void topk_final_kernel(const float* __restrict__ ce_neg,
                                  int* __restrict__ n_pos,
                                  const float* __restrict__ pb_loc,
                                  const float* __restrict__ pb_pce,
                                  const int* __restrict__ pb_npos, int npb,
                                  float* __restrict__ acc, unsigned* __restrict__ done,
                                  int N, int P, unsigned* __restrict__ out) {
    __shared__ unsigned skeys[8732];
    __shared__ int hist[4096];        // aliased as ckeys later
    __shared__ int part[1024];
    __shared__ int s_tb, s_ca, s_tb2, s_ca2, s_cnt, s_np;
    __shared__ float shf[16];
    int n = blockIdx.x, tid = threadIdx.x;

    int k;
    if (npb > 0) {                    // fused path: reduce per-block partials (wave 0)
        if (tid < 64) {
            float psl = 0.f, psp = 0.f; int psn = 0;
            for (int i = tid; i < npb; i += 64) {
                psl += pb_loc[n * npb + i];
                psp += pb_pce[n * npb + i];
                psn += pb_npos[n * npb + i];
            }
            #pragma unroll
            for (int off = 32; off >= 1; off >>= 1) {
                psl += __shfl_down(psl, off);
                psp += __shfl_down(psp, off);
                psn += __shfl_down(psn, off);
            }
            if (tid == 0) {
                s_np = psn;
                n_pos[n] = psn;                       // plain store; fenced before done++
                if (psl != 0.f) atomicAdd(&acc[0], psl);
                if (psp != 0.f) atomicAdd(&acc[1], psp);
            }
        }
        __syncthreads();
        k = 3 * s_np;
    } else {
        k = 3 * n_pos[n];
    }
    if (k > P) k = P;
    float bsum = 0.f;

    if (k > 0) {                                      // block-uniform
        const float* row = ce_neg + (size_t)n * P;
        for (int i = tid; i < P; i += TK_THREADS) skeys[i] = __float_as_uint(row[i]);
        #pragma unroll
        for (int b = 0; b < 4; ++b) hist[tid * 4 + b] = 0;
        __syncthreads();

        for (int i = tid; i < P; i += TK_THREADS) atomicAdd(&hist[skeys[i] >> 20], 1);
        __syncthreads();
        int h0 = hist[tid*4], h1 = hist[tid*4+1], h2 = hist[tid*4+2], h3 = hist[tid*4+3];
        part[tid] = h0 + h1 + h2 + h3;
        __syncthreads();
        for (int s = 1; s < 1024; s <<= 1) {
            int v = part[tid] + ((tid + s < 1024) ? part[tid + s] : 0);
            __syncthreads();
            part[tid] = v;
            __syncthreads();
        }
        int sfx = (tid + 1 < 1024) ? part[tid + 1] : 0;
        int sf3 = sfx, sf2 = sfx + h3, sf1 = sf2 + h2, sf0 = sf1 + h1;
        if (sf0 < k && k <= sf0 + h0) { s_tb = tid*4;   s_ca = sf0; }
        if (sf1 < k && k <= sf1 + h1) { s_tb = tid*4+1; s_ca = sf1; }
        if (sf2 < k && k <= sf2 + h2) { s_tb = tid*4+2; s_ca = sf2; }
        if (sf3 < k && k <= sf3 + h3) { s_tb = tid*4+3; s_ca = sf3; }
        __syncthreads();
        int tb = s_tb, kk = k - s_ca;

        if (tid < 256) part[tid] = 0;
        __syncthreads();
        float ssum = 0.f;
        for (int i = tid; i < P; i += TK_THREADS) {
            unsigned key = skeys[i];
            int bin = key >> 20;
            if (bin > tb) ssum += __uint_as_float(key);
            else if (bin == tb) atomicAdd(&part[(key >> 12) & 255u], 1);
        }
        __syncthreads();
        if (tid < 256) {
            int cum = 0;
            for (int b = tid + 1; b < 256; ++b) cum += part[b];
            int h = part[tid];
            if (cum < kk && kk <= cum + h) { s_tb2 = tid; s_ca2 = cum; }
        }
        if (tid == 0) s_cnt = 0;
        __syncthreads();
        int tb2 = s_tb2, kk2 = kk - s_ca2;

        unsigned* ckeys = (unsigned*)hist;
        for (int i = tid; i < P; i += TK_THREADS) {
            unsigned key = skeys[i];
            if ((int)(key >> 20) == tb) {
                int b2 = (key >> 12) & 255u;
                if (b2 > tb2) ssum += __uint_as_float(key);
                else if (b2 == tb2) {
                    int slot = atomicAdd(&s_cnt, 1);
                    if (slot < CK_MAX) ckeys[slot] = key;
                }
            }
        }
        __syncthreads();
        int m = s_cnt; if (m > CK_MAX) m = CK_MAX;
        for (int i = tid; i < m; i += TK_THREADS) {
            unsigned key = ckeys[i];
            int rank = 0;
            for (int j = 0; j < m; ++j) {
                unsigned kj = ckeys[j];
                rank += (kj > key) || (kj == key && j < i);
            }
            if (rank < kk2) ssum += __uint_as_float(key);
        }
        #pragma unroll
        for (int off = 32; off >= 1; off >>= 1) ssum += __shfl_down(ssum, off);
        __syncthreads();
        if ((tid & 63) == 0) shf[tid >> 6] = ssum;
        __syncthreads();
        float tot = 0.f;
        for (int i = 0; i < 16; ++i) tot += shf[i];
        bsum = tot;
    }

    if (tid == 0) {
        if (bsum != 0.f) atomicAdd(&acc[2], bsum);
        __threadfence();                              // release acc adds + n_pos store
        unsigned old = atomicAdd(done, 1u);
        if (old == (unsigned)(N - 1)) {               // last block: finalize
            float a0 = atomicAdd(&acc[0], 0.f);       // atomic reads (acquire-ish)
            float a1 = atomicAdd(&acc[1], 0.f);
            float a2 = atomicAdd(&acc[2], 0.f);
            int tot = 0;
            for (int i = 0; i < N; ++i) tot += n_pos[i];
            float npos = (float)tot;
            float conf = (a2 + a1) / npos;
            float loc  = a0 / (4.f * npos);
            float loss = conf + loc;
            unsigned ub = __float_as_uint(loss);
            unsigned r = (ub + 0x7FFFu + ((ub >> 16) & 1u)) >> 16;  // bf16 RNE
            out[0] = (r << 16) | r;
        }
    }
}

extern "C" void kernel_launch(void* const* d_in, const int* in_sizes, int n_in,
                              void* d_out, int out_size, void* d_ws, size_t ws_size,
                              hipStream_t stream) {
    const float* locs   = (const float*)d_in[0];
    const float* scores = (const float*)d_in[1];
    const float* boxes  = (const float*)d_in[2];
    const int*   labels = (const int*)d_in[3];
    const float* priors = (const float*)d_in[4];

    int P = in_sizes[4] / 4;
    long long NPl = in_sizes[0] / 4;
    int N = (int)(NPl / P);
    int C = (int)((long long)in_sizes[1] / NPl);
    int O = in_sizes[3] / N;
    size_t NP = (size_t)N * P;
    int gx = (P + SBLOCK - 1) / SBLOCK;

    char* ws = (char*)d_ws;
    float*    acc    = (float*)ws;     ws += 16;
    unsigned* done   = (unsigned*)ws;  ws += 16;
    int*      n_pos  = (int*)ws;       ws += (size_t)N * 4;
    int*      pfop   = (int*)ws;       ws += (size_t)N * O * 4;
    float*    pb_loc = (float*)ws;     ws += (size_t)N * gx * 4;
    float*    pb_pce = (float*)ws;     ws += (size_t)N * gx * 4;
    int*      pb_npos= (int*)ws;       ws += (size_t)N * gx * 4;
    int*      tcarr  = (int*)ws;       ws += NP * 4;
    float*    ce_neg = (float*)ws;     ws += NP * 4;

    match_object_kernel<<<N * O, BLOCK, 0, stream>>>(boxes, priors, pfop, acc, n_pos,
                                                     done, N, P, O);
    int npb = 0;
    if (C == 81 && (P % 4) == 0 && O <= MAXO) {
        npb = gx;
        fused_staged_kernel<<<dim3(gx, N), SBLOCK, 0, stream>>>(
            boxes, priors, locs, labels, pfop, scores, ce_neg,
            pb_loc, pb_pce, pb_npos, N, P, O);
    } else {
        int gbx = (P + BLOCK - 1) / BLOCK;
        match_prior_kernel<<<dim3(gbx, N), BLOCK, 0, stream>>>(boxes, priors, locs, labels,
                                                               pfop, tcarr, acc, n_pos, N, P, O);
        loss_generic_kernel<<<(int)((NP + BLOCK - 1) / BLOCK), BLOCK, 0, stream>>>(
            scores, tcarr, ce_neg, acc, (int)NP, C);
    }
    topk_final_kernel<<<N, TK_THREADS, 0, stream>>>(ce_neg, n_pos,
                                                    pb_loc, pb_pce, pb_npos, npb,
                                                    acc, done, N, P, (unsigned*)d_out);
}